// Round 1
// baseline (36.414 us; speedup 1.0000x reference)
//
#include <hip/hip_runtime.h>
#include <math.h>

#define NSEQ_L 4096   // sequence length L
#define NT 256        // threads per block (one block per sequence)
#define CHUNK 16      // NSEQ_L / NT elements per thread

// max-plus 2x2 compose: C = A (*) B, C[s][t] = max_k(A[s][k] + B[k][t])
__device__ __forceinline__ void mp_compose(
    float a00, float a01, float a10, float a11,
    float b00, float b01, float b10, float b11,
    float& c00, float& c01, float& c10, float& c11) {
  c00 = fmaxf(a00 + b00, a01 + b10);
  c01 = fmaxf(a00 + b01, a01 + b11);
  c10 = fmaxf(a10 + b00, a11 + b10);
  c11 = fmaxf(a10 + b01, a11 + b11);
}

// Block-wide exclusive max-plus matrix scan over 256 threads (4 waves).
// Input: this thread's chunk transform (t00..t11) in scan order.
// Output: incoming message (m0,m1) = zero-vector applied through the
// exclusive prefix of all earlier chunks.
// NOTE: caller must __syncthreads() between successive calls (wt reuse).
__device__ __forceinline__ void block_scan_msg(
    float t00, float t01, float t10, float t11,
    int lane, int w, float4* wt, float& m0, float& m1) {
  // intra-wave inclusive Hillis-Steele scan (non-commutative: earlier (*) cur)
  #pragma unroll
  for (int off = 1; off < 64; off <<= 1) {
    float o00 = __shfl_up(t00, off);
    float o01 = __shfl_up(t01, off);
    float o10 = __shfl_up(t10, off);
    float o11 = __shfl_up(t11, off);
    if (lane >= off) {
      float n00, n01, n10, n11;
      mp_compose(o00, o01, o10, o11, t00, t01, t10, t11, n00, n01, n10, n11);
      t00 = n00; t01 = n01; t10 = n10; t11 = n11;
    }
  }
  if (lane == 63) wt[w] = make_float4(t00, t01, t10, t11);  // wave total
  // intra-wave exclusive
  float e00 = __shfl_up(t00, 1);
  float e01 = __shfl_up(t01, 1);
  float e10 = __shfl_up(t10, 1);
  float e11 = __shfl_up(t11, 1);
  if (lane == 0) { e00 = 0.f; e01 = -INFINITY; e10 = -INFINITY; e11 = 0.f; }
  __syncthreads();
  // prepend earlier-wave totals: G = wt[0] (*) ... (*) wt[w-1] (*) ex
  float g00 = e00, g01 = e01, g10 = e10, g11 = e11;
  for (int ww = w - 1; ww >= 0; --ww) {
    float4 a = wt[ww];
    float n00, n01, n10, n11;
    mp_compose(a.x, a.y, a.z, a.w, g00, g01, g10, g11, n00, n01, n10, n11);
    g00 = n00; g01 = n01; g10 = n10; g11 = n11;
  }
  // apply zero init vector: m[t] = max_s(0 + G[s][t])
  m0 = fmaxf(g00, g10);
  m1 = fmaxf(g01, g11);
}

__global__ __launch_bounds__(NT, 4) void chain_fb_kernel(
    const float* __restrict__ jp, const float* __restrict__ bp,
    const int* __restrict__ obs, float* __restrict__ out) {
  __shared__ float2 fwdm[CHUNK][NT];        // 32 KB: fwd msg per element, [e][chunk]
  __shared__ unsigned short mask_s[NT];     // packed obs bits per chunk
  __shared__ float4 wt[NT / 64];            // wave totals for the scan

  const int t = threadIdx.x;
  const int lane = t & 63;
  const int w = t >> 6;
  const long b = blockIdx.x;

  const float P   = 0.25f * jp[0];   // psi = [[P,-P],[-P,P]]
  const float hb0 = 0.5f * bp[0];    // u_i = 0.5*b[obs_i]; phi_i = (-u, +u)
  const float hb1 = 0.5f * bp[1];

  // ---- load this thread's 16 obs, compute u[], pack bits for bwd pass
  const int4* rowp = (const int4*)(obs + b * NSEQ_L + (long)t * CHUNK);
  int4 q0 = rowp[0], q1 = rowp[1], q2 = rowp[2], q3 = rowp[3];
  int ov[CHUNK] = {q0.x, q0.y, q0.z, q0.w, q1.x, q1.y, q1.z, q1.w,
                   q2.x, q2.y, q2.z, q2.w, q3.x, q3.y, q3.z, q3.w};
  float u[CHUNK];
  unsigned mbits = 0;
  #pragma unroll
  for (int e = 0; e < CHUNK; ++e) {
    u[e] = ov[e] ? hb1 : hb0;
    mbits |= (unsigned)(ov[e] & 1) << e;
  }
  mask_s[t] = (unsigned short)mbits;

  // ---- forward chunk transform: E(u0) (*) E(u1) ... ; E[s][t] = phi[s]+psi[s][t]
  float t00 = P - u[0], t01 = -u[0] - P, t10 = u[0] - P, t11 = u[0] + P;
  #pragma unroll
  for (int e = 1; e < CHUNK; ++e) {
    float x0 = t00 - u[e], y0 = t01 + u[e];
    float x1 = t10 - u[e], y1 = t11 + u[e];
    t00 = fmaxf(x0 + P, y0 - P); t01 = fmaxf(x0 - P, y0 + P);
    t10 = fmaxf(x1 + P, y1 - P); t11 = fmaxf(x1 - P, y1 + P);
  }

  float m0, m1;
  block_scan_msg(t00, t01, t10, t11, lane, w, wt, m0, m1);

  // ---- forward replay: fwd[i] = msg BEFORE consuming element i
  #pragma unroll
  for (int e = 0; e < CHUNK; ++e) {
    fwdm[e][t] = make_float2(m0, m1);
    float x = m0 - u[e], y = m1 + u[e];
    m0 = fmaxf(x + P, y - P);
    m1 = fmaxf(x - P, y + P);
  }
  __syncthreads();  // fwdm visible; wt reads done (safe to overwrite)

  // ---- backward: thread c handles mirrored chunk (fwd chunk NT-1-c), reversed
  unsigned bm = mask_s[NT - 1 - t];
  float ub[CHUNK];
  #pragma unroll
  for (int e = 0; e < CHUNK; ++e) ub[e] = ((bm >> e) & 1) ? hb1 : hb0;

  // compose in reverse element order: E(u15) (*) E(u14) ... (*) E(u0)
  float s00 = P - ub[15], s01 = -ub[15] - P, s10 = ub[15] - P, s11 = ub[15] + P;
  #pragma unroll
  for (int e = CHUNK - 2; e >= 0; --e) {
    float x0 = s00 - ub[e], y0 = s01 + ub[e];
    float x1 = s10 - ub[e], y1 = s11 + ub[e];
    s00 = fmaxf(x0 + P, y0 - P); s01 = fmaxf(x0 - P, y0 + P);
    s10 = fmaxf(x1 + P, y1 - P); s11 = fmaxf(x1 - P, y1 + P);
  }

  block_scan_msg(s00, s01, s10, s11, lane, w, wt, m0, m1);

  // ---- backward replay fused with output: out = phi + fwd + bwd
  float o0[CHUNK], o1[CHUNK];
  #pragma unroll
  for (int e = CHUNK - 1; e >= 0; --e) {
    float2 f = fwdm[e][NT - 1 - t];
    o0[e] = f.x - ub[e] + m0;   // state 0: phi = -u
    o1[e] = f.y + ub[e] + m1;   // state 1: phi = +u
    float x = m0 - ub[e], y = m1 + ub[e];
    m0 = fmaxf(x + P, y - P);
    m1 = fmaxf(x - P, y + P);
  }

  const long base = (long)(NT - 1 - t) * CHUNK;   // 16-aligned, 64B-aligned
  float* r0 = out + b * (2L * NSEQ_L) + base;     // out[b][0][base..]
  float* r1 = r0 + NSEQ_L;                        // out[b][1][base..]
  #pragma unroll
  for (int v = 0; v < CHUNK / 4; ++v) {
    ((float4*)r0)[v] = make_float4(o0[4*v], o0[4*v+1], o0[4*v+2], o0[4*v+3]);
    ((float4*)r1)[v] = make_float4(o1[4*v], o1[4*v+1], o1[4*v+2], o1[4*v+3]);
  }
}

extern "C" void kernel_launch(void* const* d_in, const int* in_sizes, int n_in,
                              void* d_out, int out_size, void* d_ws, size_t ws_size,
                              hipStream_t stream) {
  const float* jp = (const float*)d_in[0];
  const float* bp = (const float*)d_in[1];
  const int*   obs = (const int*)d_in[2];
  float* out = (float*)d_out;
  const int B = in_sizes[2] / NSEQ_L;   // 2048
  chain_fb_kernel<<<B, NT, 0, stream>>>(jp, bp, obs, out);
}

// Round 2
// 25.724 us; speedup vs baseline: 1.4155x; 1.4155x over previous
//
#include <hip/hip_runtime.h>
#include <math.h>

#define L_SEQ 4096   // sequence length L
#define NT 512       // threads per block (one block per sequence)
#define CHUNK 8      // L_SEQ / NT elements per thread
#define NW (NT/64)   // waves per block

struct M2 { float a00, a01, a10, a11; };

// max-plus 2x2 compose: C[s][t] = max_k(A[s][k] + B[k][t])
__device__ __forceinline__ M2 mpc(const M2& A, const M2& B) {
  M2 C;
  C.a00 = fmaxf(A.a00 + B.a00, A.a01 + B.a10);
  C.a01 = fmaxf(A.a00 + B.a01, A.a01 + B.a11);
  C.a10 = fmaxf(A.a10 + B.a00, A.a11 + B.a10);
  C.a11 = fmaxf(A.a10 + B.a01, A.a11 + B.a11);
  return C;
}

__global__ __launch_bounds__(NT, 8) void chain_fb_kernel(
    const float* __restrict__ jp, const float* __restrict__ bp,
    const int* __restrict__ obs, float* __restrict__ out) {
  __shared__ float4 wtf[NW];   // forward wave totals
  __shared__ float4 wtb[NW];   // backward wave totals

  const int t = threadIdx.x;
  const int lane = t & 63;
  const int w = t >> 6;
  const long b = blockIdx.x;

  const float P   = 0.25f * jp[0];   // psi = [[P,-P],[-P,P]]
  const float hb0 = 0.5f * bp[0];    // u_i = 0.5*b[obs_i]; phi_i = (-u, +u)
  const float hb1 = 0.5f * bp[1];

  // ---- load this thread's 8 obs (contiguous 32B, coalesced)
  const int4* rowp = (const int4*)(obs + b * L_SEQ + (long)t * CHUNK);
  int4 q0 = rowp[0], q1 = rowp[1];
  int ov[CHUNK] = {q0.x, q0.y, q0.z, q0.w, q1.x, q1.y, q1.z, q1.w};
  float u[CHUNK];
  #pragma unroll
  for (int e = 0; e < CHUNK; ++e) u[e] = ov[e] ? hb1 : hb0;

  // ---- fwd chunk transform T = E(u0)(*)...(*)E(u7); E=[[P-u,-u-P],[u-P,u+P]]
  M2 T{P - u[0], -u[0] - P, u[0] - P, u[0] + P};
  #pragma unroll
  for (int e = 1; e < CHUNK; ++e) {
    float x0 = T.a00 - u[e], y0 = T.a01 + u[e];
    float x1 = T.a10 - u[e], y1 = T.a11 + u[e];
    T.a00 = fmaxf(x0 + P, y0 - P); T.a01 = fmaxf(x0 - P, y0 + P);
    T.a10 = fmaxf(x1 + P, y1 - P); T.a11 = fmaxf(x1 - P, y1 + P);
  }
  // ---- bwd chunk transform R = E(u7)(*)...(*)E(u0)
  M2 R{P - u[CHUNK-1], -u[CHUNK-1] - P, u[CHUNK-1] - P, u[CHUNK-1] + P};
  #pragma unroll
  for (int e = CHUNK - 2; e >= 0; --e) {
    float x0 = R.a00 - u[e], y0 = R.a01 + u[e];
    float x1 = R.a10 - u[e], y1 = R.a11 + u[e];
    R.a00 = fmaxf(x0 + P, y0 - P); R.a01 = fmaxf(x0 - P, y0 + P);
    R.a10 = fmaxf(x1 + P, y1 - P); R.a11 = fmaxf(x1 - P, y1 + P);
  }

  // ---- fused Hillis-Steele scans: prefix (shfl_up) + suffix (shfl_down)
  // Two independent dependency chains -> ILP during shuffle latency.
  #pragma unroll
  for (int off = 1; off < 64; off <<= 1) {
    M2 OF{__shfl_up(T.a00, off), __shfl_up(T.a01, off),
          __shfl_up(T.a10, off), __shfl_up(T.a11, off)};
    M2 OB{__shfl_down(R.a00, off), __shfl_down(R.a01, off),
          __shfl_down(R.a10, off), __shfl_down(R.a11, off)};
    if (lane >= off)      T = mpc(OF, T);   // earlier-in-order on the left
    if (lane < 64 - off)  R = mpc(OB, R);   // higher-index on the left
  }
  if (lane == 63) wtf[w] = make_float4(T.a00, T.a01, T.a10, T.a11);
  if (lane == 0)  wtb[w] = make_float4(R.a00, R.a01, R.a10, R.a11);

  // intra-wave exclusive versions
  M2 EF{__shfl_up(T.a00, 1), __shfl_up(T.a01, 1),
        __shfl_up(T.a10, 1), __shfl_up(T.a11, 1)};
  M2 EB{__shfl_down(R.a00, 1), __shfl_down(R.a01, 1),
        __shfl_down(R.a10, 1), __shfl_down(R.a11, 1)};
  if (lane == 0)  { EF.a00 = 0.f; EF.a01 = -INFINITY; EF.a10 = -INFINITY; EF.a11 = 0.f; }
  if (lane == 63) { EB.a00 = 0.f; EB.a01 = -INFINITY; EB.a10 = -INFINITY; EB.a11 = 0.f; }

  __syncthreads();  // the ONLY barrier: wave totals visible

  // prepend other-wave totals (fwd: waves < w, left-composed descending;
  // bwd: waves > w, left-composed ascending)
  M2 GF = EF, GB = EB;
  for (int ww = w - 1; ww >= 0; --ww) {
    float4 a = wtf[ww];
    GF = mpc(M2{a.x, a.y, a.z, a.w}, GF);
  }
  for (int ww = w + 1; ww < NW; ++ww) {
    float4 a = wtb[ww];
    GB = mpc(M2{a.x, a.y, a.z, a.w}, GB);
  }
  // apply zero init vector: m[t] = max_s G[s][t]
  float fm0 = fmaxf(GF.a00, GF.a10), fm1 = fmaxf(GF.a01, GF.a11);
  float bm0 = fmaxf(GB.a00, GB.a10), bm1 = fmaxf(GB.a01, GB.a11);

  // ---- fwd replay: o = phi + fwd  (x,y are exactly phi+msg)
  float o0[CHUNK], o1[CHUNK];
  #pragma unroll
  for (int e = 0; e < CHUNK; ++e) {
    float x = fm0 - u[e], y = fm1 + u[e];
    o0[e] = x; o1[e] = y;
    fm0 = fmaxf(x + P, y - P);
    fm1 = fmaxf(x - P, y + P);
  }
  // ---- bwd replay: add bwd message (before consuming element e, going right->left)
  #pragma unroll
  for (int e = CHUNK - 1; e >= 0; --e) {
    o0[e] += bm0; o1[e] += bm1;
    float x = bm0 - u[e], y = bm1 + u[e];
    bm0 = fmaxf(x + P, y - P);
    bm1 = fmaxf(x - P, y + P);
  }

  // ---- store: each thread owns contiguous 8 floats per state row (coalesced)
  const long base = (long)t * CHUNK;
  float* r0 = out + b * (2L * L_SEQ) + base;   // out[b][0][base..]
  float* r1 = r0 + L_SEQ;                      // out[b][1][base..]
  ((float4*)r0)[0] = make_float4(o0[0], o0[1], o0[2], o0[3]);
  ((float4*)r0)[1] = make_float4(o0[4], o0[5], o0[6], o0[7]);
  ((float4*)r1)[0] = make_float4(o1[0], o1[1], o1[2], o1[3]);
  ((float4*)r1)[1] = make_float4(o1[4], o1[5], o1[6], o1[7]);
}

extern "C" void kernel_launch(void* const* d_in, const int* in_sizes, int n_in,
                              void* d_out, int out_size, void* d_ws, size_t ws_size,
                              hipStream_t stream) {
  const float* jp  = (const float*)d_in[0];
  const float* bp  = (const float*)d_in[1];
  const int*   obs = (const int*)d_in[2];
  float* out = (float*)d_out;
  const int B = in_sizes[2] / L_SEQ;   // 2048
  chain_fb_kernel<<<B, NT, 0, stream>>>(jp, bp, obs, out);
}